// Round 7
// baseline (3493.447 us; speedup 1.0000x reference)
//
#include <hip/hip_runtime.h>
#include <math.h>

#define K_NN 11
#define B_   1024
#define D_   64
#define A_   4
#define C_   50000
#define NCH  4
#define CPC  12500               // candidates per chunk
#define NTT  49                  // 256-wide c-tiles per chunk (48 full + 212 tail)
#define TW   256                 // tile width (candidates)
#define LDP  260                 // padded floats per d-row (16B-aligned, 4-bank skew)

// ---------------- K0: s2[a,c] = sum(ts[a,c,:]^2) ----------------
__global__ __launch_bounds__(256) void s2_kernel(const float* __restrict__ ts,
                                                 float* __restrict__ s2g) {
  const int gwid = (blockIdx.x * 256 + threadIdx.x) >> 6;
  const int lane = threadIdx.x & 63;
  const int r0 = gwid * 16;
  if (r0 >= A_ * C_) return;
  const float4* t4 = (const float4*)ts;
  #pragma unroll
  for (int i = 0; i < 4; ++i) {
    const int fi = i * 64 + lane;
    const int r  = r0 + (fi >> 4);
    const int k  = fi & 15;
    float4 v = t4[(size_t)r * 16 + k];
    float acc = v.x*v.x + v.y*v.y + v.z*v.z + v.w*v.w;
    #pragma unroll
    for (int off = 1; off < 16; off <<= 1) acc += __shfl_xor(acc, off, 64);
    if ((lane & 15) == 0) s2g[r] = acc;
  }
}

// ---------------- K1: d-major LDS, m=8 rows/wave, coalesced staging --------
// grid 512 = 32 rowgroups x 4 a x 4 ch; block 256 thr = 4 waves, 8 rows/wave.
// Staging: thread t owns cands 8q..8q+7 (q=t>>3) at dim-quad k=t&7 ->
// global reads are 8 runs of 8 consecutive float4s (coalesced 128B segments);
// LDS writes are ds_write_b128 (4 cands x 1 dim), col-block ^ (d&7) swizzle.
// Compute: lane reads cands 4*lane..+3 at dim dl (b128, same swizzle), obs
// broadcast via readlane from distributed o[r]. Lists: lane r owns row r.

#define INSERT(SC, CI, R, VCHK)                                              \
  {                                                                          \
    const int cid = c0 + 4 * lane + (CI);                                    \
    const bool pass = ((VCHK) ? (cid < cend) : true) &&                      \
        ((SC) < tau[R] || ((SC) == tau[R] && cid < tix[R]));                 \
    unsigned long long m_ = __ballot(pass);                                  \
    while (m_) {                                                             \
      const int l_ = __ffsll(m_) - 1;                                        \
      m_ &= m_ - 1;                                                          \
      const float ssc = __uint_as_float(                                     \
          __builtin_amdgcn_readlane(__float_as_uint(SC), l_));               \
      const int sid = c0 + 4 * l_ + (CI);                                    \
      if ((ssc < tau[R]) || (ssc == tau[R] && sid < tix[R])) {               \
        const bool own = (lane == (R));                                      \
        _Pragma("unroll")                                                    \
        for (int j = K_NN - 1; j >= 1; --j) {                                \
          const bool  s1 = (best[j-1] > ssc) ||                              \
                           (best[j-1] == ssc && bix[j-1] > sid);             \
          const float nb = s1 ? best[j-1] : ssc;                             \
          const int   ni = s1 ? bix[j-1]  : sid;                             \
          const bool  wr = own && ((best[j] > ssc) ||                        \
                                   (best[j] == ssc && bix[j] > sid));        \
          best[j] = wr ? nb : best[j];                                       \
          bix[j]  = wr ? ni : bix[j];                                        \
        }                                                                    \
        const bool w0 = own && ((best[0] > ssc) ||                           \
                                (best[0] == ssc && bix[0] > sid));           \
        bix[0]  = w0 ? sid : bix[0];                                         \
        best[0] = w0 ? ssc : best[0];                                        \
        tau[R] = __uint_as_float(                                            \
            __builtin_amdgcn_readlane(__float_as_uint(best[K_NN-1]), (R)));  \
        tix[R] = __builtin_amdgcn_readlane(bix[K_NN-1], (R));                \
      }                                                                      \
    }                                                                        \
  }

#define SELECT(MASKED)                                                       \
  {                                                                          \
    _Pragma("unroll")                                                        \
    for (int r = 0; r < 8; ++r) {                                            \
      float e0 = fmaf(-2.f, acc[r][0], sq4.x);                               \
      float e1 = fmaf(-2.f, acc[r][1], sq4.y);                               \
      float e2 = fmaf(-2.f, acc[r][2], sq4.z);                               \
      float e3 = fmaf(-2.f, acc[r][3], sq4.w);                               \
      if (MASKED) {                                                          \
        if (c0 + 4 * lane + 0 >= cend) e0 = INFINITY;                        \
        if (c0 + 4 * lane + 1 >= cend) e1 = INFINITY;                        \
        if (c0 + 4 * lane + 2 >= cend) e2 = INFINITY;                        \
        if (c0 + 4 * lane + 3 >= cend) e3 = INFINITY;                        \
      }                                                                      \
      const float mn = fminf(fminf(e0, e1), fminf(e2, e3));                  \
      if (__ballot(mn <= tau[r])) {                                          \
        INSERT(e0, 0, r, MASKED)                                             \
        INSERT(e1, 1, r, MASKED)                                             \
        INSERT(e2, 2, r, MASKED)                                             \
        INSERT(e3, 3, r, MASKED)                                             \
      }                                                                      \
    }                                                                        \
  }

// LOADS: 8 coalesced float4 loads (cands cb..cb+7 at dims H*32+4k..+3)
#define LOADS(T, H)                                                          \
  {                                                                          \
    const int cb = cbase + (T) * TW + stq * 8;                               \
    _Pragma("unroll")                                                        \
    for (int j = 0; j < 8; ++j) {                                            \
      const int c = min(cb + j, C_ - 1);                                     \
      stg[j] = *(const float4*)(tsa + (size_t)c * 64 + (H) * 32 + 4 * stk);  \
    }                                                                        \
  }

// WRITES: 8 ds_write_b128, d-major, col-block ^ (d&7) swizzle
#define WR1(SB, I, COMP)                                                     \
  {                                                                          \
    const int d = 4 * stk + (I);                                             \
    const int s_ = d & 7;                                                    \
    *(float4*)&(SB)[d * LDP + 4 * ((2 * stq) ^ s_)] =                        \
        make_float4(stg[0].COMP, stg[1].COMP, stg[2].COMP, stg[3].COMP);     \
    *(float4*)&(SB)[d * LDP + 4 * ((2 * stq + 1) ^ s_)] =                    \
        make_float4(stg[4].COMP, stg[5].COMP, stg[6].COMP, stg[7].COMP);     \
  }
#define WRITES(SB) { WR1(SB, 0, x) WR1(SB, 1, y) WR1(SB, 2, z) WR1(SB, 3, w) }

// COMPUTE: 32 d-steps; lane reads its 4 cands (b128), 8 readlane broadcasts
#define COMPUTE(SB, H)                                                       \
  {                                                                          \
    _Pragma("unroll")                                                        \
    for (int dl = 0; dl < 32; ++dl) {                                        \
      const float4 cv =                                                      \
          *(const float4*)&(SB)[dl * LDP + 4 * (lane ^ (dl & 7))];           \
      _Pragma("unroll")                                                      \
      for (int r = 0; r < 8; ++r) {                                          \
        const float ov = __uint_as_float(                                    \
            __builtin_amdgcn_readlane(__float_as_uint(o[r]),                 \
                                      (H) * 32 + dl));                       \
        acc[r][0] = fmaf(cv.x, ov, acc[r][0]);                               \
        acc[r][1] = fmaf(cv.y, ov, acc[r][1]);                               \
        acc[r][2] = fmaf(cv.z, ov, acc[r][2]);                               \
        acc[r][3] = fmaf(cv.w, ov, acc[r][3]);                               \
      }                                                                      \
    }                                                                        \
  }

__global__ __launch_bounds__(256) void qec_kernel(
    const float* __restrict__ obs, const float* __restrict__ ts,
    const float* __restrict__ s2g, float* __restrict__ pscore,
    int* __restrict__ pidx)
{
  __shared__ float sb0[32 * LDP];           // 33,280 B (half-tile, dims 0..31)
  __shared__ float sb1[32 * LDP];           // 33,280 B (dims 32..63)

  const int tid  = threadIdx.x;
  const int lane = tid & 63;
  const int w    = tid >> 6;
  const int x    = blockIdx.x & 15;         // (a,ch): XCD slice locality
  const int a    = x >> 2;
  const int ch   = x & 3;
  const int rg   = blockIdx.x >> 4;         // 0..31
  const int b0w  = rg * 32 + w * 8;         // this wave's 8 rows

  const float* tsa = ts  + (size_t)a * C_ * 64;
  const float* s2a = s2g + (size_t)a * C_;
  const int cbase = ch * CPC;
  const int cend  = cbase + CPC;

  // distributed obs: o[r] = obs[b0w+r][lane]  (8 VGPRs)
  float o[8];
  #pragma unroll
  for (int r = 0; r < 8; ++r) o[r] = obs[(size_t)(b0w + r) * 64 + lane];

  float best[K_NN]; int bix[K_NN];
  float tau[8]; int tix[8];
  #pragma unroll
  for (int j = 0; j < K_NN; ++j) { best[j] = INFINITY; bix[j] = 0x7fffffff; }
  #pragma unroll
  for (int r = 0; r < 8; ++r) { tau[r] = INFINITY; tix[r] = 0x7fffffff; }

  const int stq = tid >> 3;                 // 0..31: cand octet
  const int stk = tid & 7;                  // 0..7 : dim quad
  float4 stg[8];
  float acc[8][4];
  float4 sq4;

  // prologue: stage tile 0 half 0
  LOADS(0, 0);
  WRITES(sb0);
  __syncthreads();

  for (int T = 0; T < NTT; ++T) {
    const int c0 = cbase + T * TW;

    // ---- half 0 (dims 0..31) ----
    LOADS(T, 1);                            // prefetch half 1 (coalesced)
    #pragma unroll
    for (int r = 0; r < 8; ++r) {
      acc[r][0] = 0.f; acc[r][1] = 0.f; acc[r][2] = 0.f; acc[r][3] = 0.f;
    }
    sq4 = *(const float4*)(s2a + min(c0 + 4 * lane, C_ - 4));
    COMPUTE(sb0, 0);
    __syncthreads();
    WRITES(sb1);
    __syncthreads();

    // ---- half 1 (dims 32..63) ----
    if (T + 1 < NTT) LOADS(T + 1, 0);       // prefetch next tile half 0
    COMPUTE(sb1, 1);
    if (c0 + TW <= cend) { SELECT(false) } else { SELECT(true) }
    __syncthreads();
    if (T + 1 < NTT) { WRITES(sb0); __syncthreads(); }
  }

  // epilogue: lane r (0..7) owns row b0w+r
  if (lane < 8) {
    const int b = b0w + lane;
    const size_t base = (((size_t)b * A_ + a) * NCH + ch) * K_NN;
    #pragma unroll
    for (int j = 0; j < K_NN; ++j) {
      pscore[base + j] = best[j];
      pidx[base + j]   = bix[j];
    }
  }
}

// ---------------- K2: merge partial top-k, gather qvals, mean ----------------
__global__ __launch_bounds__(256) void merge_kernel(
    const float* __restrict__ pscore, const int* __restrict__ pidx,
    const float* __restrict__ qvals, float* __restrict__ qec)
{
  const int tt = blockIdx.x * 256 + threadIdx.x;  // tt = b*A + a
  if (tt >= B_ * A_) return;
  const int a = tt % A_;

  float best[K_NN]; int bix[K_NN];
  #pragma unroll
  for (int j = 0; j < K_NN; ++j) { best[j] = INFINITY; bix[j] = 0x7fffffff; }

  const float* ps = pscore + (size_t)tt * NCH * K_NN;
  const int*   pi = pidx   + (size_t)tt * NCH * K_NN;

  #pragma unroll
  for (int e = 0; e < NCH * K_NN; ++e) {
    float sc = ps[e]; int ci = pi[e];
    bool lt_last = (sc < best[K_NN-1]) || (sc == best[K_NN-1] && ci < bix[K_NN-1]);
    if (lt_last) {
      #pragma unroll
      for (int j = K_NN-1; j >= 1; --j) {
        bool  s1 = (best[j-1] > sc) || (best[j-1] == sc && bix[j-1] > ci);
        float nb = s1 ? best[j-1] : sc;
        int   ni = s1 ? bix[j-1]  : ci;
        bool  wr = (best[j] > sc) || (best[j] == sc && bix[j] > ci);
        if (wr) { best[j] = nb; bix[j] = ni; }
      }
      bool w0 = (best[0] > sc) || (best[0] == sc && bix[0] > ci);
      if (w0) { best[0] = sc; bix[0] = ci; }
    }
  }

  const float* qa = qvals + (size_t)a * C_;
  float s = 0.f;
  #pragma unroll
  for (int j = 0; j < K_NN; ++j) s += qa[bix[j]];
  qec[tt] = s / (float)K_NN;
}

// ---------------- K3: MLP + combine + argmax ----------------
__global__ __launch_bounds__(256) void mlp_kernel(
    const float* __restrict__ obs, const float* __restrict__ qec,
    const float* __restrict__ W1, const float* __restrict__ b1,
    const float* __restrict__ W2, const float* __restrict__ b2,
    const float* __restrict__ W3, const float* __restrict__ b3,
    float* __restrict__ out)
{
  const int wave = threadIdx.x >> 6;
  const int lane = threadIdx.x & 63;
  const int b = blockIdx.x * 4 + wave;

  float xv = obs[(size_t)b * 64 + lane];

  float acc = b1[lane];
  #pragma unroll 8
  for (int d = 0; d < 64; ++d)
    acc = fmaf(__shfl(xv, d, 64), W1[d * 64 + lane], acc);
  float h1 = fmaxf(acc, 0.f);

  float acc2 = b2[lane];
  #pragma unroll 8
  for (int d = 0; d < 64; ++d)
    acc2 = fmaf(__shfl(h1, d, 64), W2[d * 64 + lane], acc2);
  float h2 = fmaxf(acc2, 0.f);

  float p0 = h2 * W3[lane * 4 + 0];
  float p1 = h2 * W3[lane * 4 + 1];
  float p2 = h2 * W3[lane * 4 + 2];
  float p3 = h2 * W3[lane * 4 + 3];
  #pragma unroll
  for (int off = 32; off > 0; off >>= 1) {
    p0 += __shfl_xor(p0, off, 64);
    p1 += __shfl_xor(p1, off, 64);
    p2 += __shfl_xor(p2, off, 64);
    p3 += __shfl_xor(p3, off, 64);
  }

  if (lane == 0) {
    float q0 = 0.5f * (qec[b * 4 + 0] + (p0 + b3[0]));
    float q1 = 0.5f * (qec[b * 4 + 1] + (p1 + b3[1]));
    float q2 = 0.5f * (qec[b * 4 + 2] + (p2 + b3[2]));
    float q3 = 0.5f * (qec[b * 4 + 3] + (p3 + b3[3]));
    int am = 0; float m = q0;
    if (q1 > m) { m = q1; am = 1; }
    if (q2 > m) { m = q2; am = 2; }
    if (q3 > m) { m = q3; am = 3; }
    out[b] = (float)am;
    float* qrow = out + B_ + (size_t)b * 4;
    qrow[0] = q0; qrow[1] = q1; qrow[2] = q2; qrow[3] = q3;
  }
}

extern "C" void kernel_launch(void* const* d_in, const int* in_sizes, int n_in,
                              void* d_out, int out_size, void* d_ws, size_t ws_size,
                              hipStream_t stream) {
  const float* obs = (const float*)d_in[0];
  const float* ts  = (const float*)d_in[1];
  const float* qv  = (const float*)d_in[2];
  const float* W1  = (const float*)d_in[3];
  const float* b1  = (const float*)d_in[4];
  const float* W2  = (const float*)d_in[5];
  const float* b2  = (const float*)d_in[6];
  const float* W3  = (const float*)d_in[7];
  const float* b3  = (const float*)d_in[8];
  float* out = (float*)d_out;

  float* s2g    = (float*)d_ws;                                   // A*C
  float* qec    = s2g + (size_t)A_ * C_;                          // B*A
  float* pscore = qec + (size_t)B_ * A_;                          // B*A*NCH*K
  int*   pidx   = (int*)(pscore + (size_t)B_ * A_ * NCH * K_NN);  // same

  s2_kernel<<<dim3((A_ * C_ / 16 + 3) / 4), dim3(256), 0, stream>>>(ts, s2g);
  qec_kernel<<<dim3(512), dim3(256), 0, stream>>>(obs, ts, s2g, pscore, pidx);
  merge_kernel<<<dim3((B_ * A_ + 255) / 256), dim3(256), 0, stream>>>(pscore, pidx, qv, qec);
  mlp_kernel<<<dim3(B_ / 4), dim3(256), 0, stream>>>(obs, qec, W1, b1, W2, b2, W3, b3, out);
}

// Round 8
// 1867.492 us; speedup vs baseline: 1.8707x; 1.8707x over previous
//
#include <hip/hip_runtime.h>
#include <math.h>

#define K_NN 11
#define B_   1024
#define D_   64
#define A_   4
#define C_   50000
#define NCH  2
#define CPC  25000               // candidates per chunk
#define NTPC 391                 // ceil(25000/64) tiles per chunk
#define RW   68                  // padded LDS row stride (floats): bank-uniform
#define TSZ  (64 * RW)           // 4352 floats = 17,408 B per buffer

// ---------------- K0: s2[a,c] = sum(ts[a,c,:]^2) ----------------
__global__ __launch_bounds__(256) void s2_kernel(const float* __restrict__ ts,
                                                 float* __restrict__ s2g) {
  const int gwid = (blockIdx.x * 256 + threadIdx.x) >> 6;
  const int lane = threadIdx.x & 63;
  const int r0 = gwid * 16;
  if (r0 >= A_ * C_) return;
  const float4* t4 = (const float4*)ts;
  #pragma unroll
  for (int i = 0; i < 4; ++i) {
    const int fi = i * 64 + lane;
    const int r  = r0 + (fi >> 4);
    const int k  = fi & 15;
    float4 v = t4[(size_t)r * 16 + k];
    float acc = v.x*v.x + v.y*v.y + v.z*v.z + v.w*v.w;
    #pragma unroll
    for (int off = 1; off < 16; off <<= 1) acc += __shfl_xor(acc, off, 64);
    if ((lane & 15) == 0) s2g[r] = acc;
  }
}

// ---------------- K1: r2 skeleton + pad-68 layout + dim-split m=4 ----------
// grid 256 = 32 rowgroups x 4 a x 2 ch ((a,ch)=bid&7 -> per-XCD slice).
// block 512 thr = 8 waves; wave owns 4 rows. Lane half h=lane>>5 covers dims
// 32h..32h+31; lane-pair (u, u+32) covers cands u and u+32 of each 64-tile.
// Partial dots combined by shfl_xor(32)+add (exact). Lists: lane r owns row r.

#define SEL1(SCV, CID0, R)                                                   \
  {                                                                          \
    const int cid_ = (CID0) + u;                                             \
    const bool pass_ = (cid_ < cend) &&                                      \
        ((SCV) < tau[R] || ((SCV) == tau[R] && cid_ < tix[R]));              \
    unsigned long long m_ = __ballot(pass_) & 0xffffffffull;                 \
    while (m_) {                                                             \
      const int l_ = __ffsll(m_) - 1;                                        \
      m_ &= m_ - 1;                                                          \
      const float ssc = __uint_as_float(                                     \
          __builtin_amdgcn_readlane(__float_as_uint(SCV), l_));              \
      const int sid = (CID0) + l_;                                           \
      if ((ssc < tau[R]) || (ssc == tau[R] && sid < tix[R])) {               \
        const bool own = (lane == (R));                                      \
        _Pragma("unroll")                                                    \
        for (int j = K_NN - 1; j >= 1; --j) {                                \
          const bool  s1 = (best[j-1] > ssc) ||                              \
                           (best[j-1] == ssc && bix[j-1] > sid);             \
          const float nb = s1 ? best[j-1] : ssc;                             \
          const int   ni = s1 ? bix[j-1]  : sid;                             \
          const bool  wr = own && ((best[j] > ssc) ||                        \
                                   (best[j] == ssc && bix[j] > sid));        \
          best[j] = wr ? nb : best[j];                                       \
          bix[j]  = wr ? ni : bix[j];                                        \
        }                                                                    \
        const bool w0 = own && ((best[0] > ssc) ||                           \
                                (best[0] == ssc && bix[0] > sid));           \
        bix[0]  = w0 ? sid : bix[0];                                         \
        best[0] = w0 ? ssc : best[0];                                        \
        tau[R] = __uint_as_float(                                            \
            __builtin_amdgcn_readlane(__float_as_uint(best[K_NN-1]), (R)));  \
        tix[R] = __builtin_amdgcn_readlane(bix[K_NN-1], (R));                \
      }                                                                      \
    }                                                                        \
  }

// coalesced global loads: f = tid + 512j -> cand c0t+(f>>4), float4 (f&15)
#define LOADS(T)                                                             \
  {                                                                          \
    const int cb = cbase + (T) * 64;                                         \
    _Pragma("unroll")                                                        \
    for (int j = 0; j < 2; ++j) {                                            \
      const int f = tid + 512 * j;                                           \
      const int c = min(cb + (f >> 4), C_ - 1);                              \
      stg[j] = *(const float4*)(tsa + (size_t)c * 64 + 4 * (f & 15));        \
    }                                                                        \
  }
// pad-68 writes: quad=(c+k)%8 uniform -> conflict-free
#define WRITES(BUF)                                                          \
  {                                                                          \
    float* dst = &sb[BUF][0];                                                \
    _Pragma("unroll")                                                        \
    for (int j = 0; j < 2; ++j) {                                            \
      const int f = tid + 512 * j;                                           \
      *(float4*)&dst[(f >> 4) * RW + 4 * (f & 15)] = stg[j];                 \
    }                                                                        \
  }

__global__ __launch_bounds__(512) void qec_kernel(
    const float* __restrict__ obs, const float* __restrict__ ts,
    const float* __restrict__ s2g, float* __restrict__ pscore,
    int* __restrict__ pidx)
{
  __shared__ float sb[2][TSZ];              // 34,816 B

  const int tid  = threadIdx.x;
  const int lane = tid & 63;
  const int w    = tid >> 6;
  const int e    = blockIdx.x & 7;          // XCD slice id
  const int a    = e >> 1;
  const int ch   = e & 1;
  const int rg   = blockIdx.x >> 3;         // 0..31
  const int b0w  = rg * 32 + w * 4;         // this wave's 4 rows

  const int h = lane >> 5;                  // dim half (0: d 0..31, 1: d 32..63)
  const int u = lane & 31;                  // cand sub-index

  const float* tsa = ts  + (size_t)a * C_ * 64;
  const float* s2a = s2g + (size_t)a * C_;
  const int cbase = ch * CPC;
  const int cend  = cbase + CPC;

  // obs half-rows: o[r][q] = obs[b0w+r][32h+4q .. +3]   (128 VGPR)
  float4 o[4][8];
  #pragma unroll
  for (int r = 0; r < 4; ++r)
    #pragma unroll
    for (int q = 0; q < 8; ++q)
      o[r][q] = *(const float4*)(obs + (size_t)(b0w + r) * 64 + 32 * h + 4 * q);

  float best[K_NN]; int bix[K_NN];
  float tau[4]; int tix[4];
  #pragma unroll
  for (int j = 0; j < K_NN; ++j) { best[j] = INFINITY; bix[j] = 0x7fffffff; }
  #pragma unroll
  for (int r = 0; r < 4; ++r) { tau[r] = INFINITY; tix[r] = 0x7fffffff; }

  float4 stg[2];

  LOADS(0);

  for (int T = 0; T < NTPC; ++T) {
    const int c0 = cbase + T * 64;

    WRITES(T & 1);
    if (T + 1 < NTPC) LOADS(T + 1);
    const float sA = s2a[min(c0 + u, C_ - 1)];
    const float sB = s2a[min(c0 + 32 + u, C_ - 1)];

    __syncthreads();

    // compute: lane's cands u and u+32, its 32 dims; pad-68 reads uniform
    float accA[4] = {0.f, 0.f, 0.f, 0.f};
    float accB[4] = {0.f, 0.f, 0.f, 0.f};
    {
      const float* bp = &sb[T & 1][0];
      const int baseA = u * RW + 32 * h;
      const int baseB = (u + 32) * RW + 32 * h;
      #pragma unroll
      for (int q = 0; q < 8; ++q) {
        const float4 cA = *(const float4*)&bp[baseA + 4 * q];
        const float4 cB = *(const float4*)&bp[baseB + 4 * q];
        #pragma unroll
        for (int r = 0; r < 4; ++r) {
          accA[r] = fmaf(cA.x, o[r][q].x, accA[r]);
          accA[r] = fmaf(cA.y, o[r][q].y, accA[r]);
          accA[r] = fmaf(cA.z, o[r][q].z, accA[r]);
          accA[r] = fmaf(cA.w, o[r][q].w, accA[r]);
          accB[r] = fmaf(cB.x, o[r][q].x, accB[r]);
          accB[r] = fmaf(cB.y, o[r][q].y, accB[r]);
          accB[r] = fmaf(cB.z, o[r][q].z, accB[r]);
          accB[r] = fmaf(cB.w, o[r][q].w, accB[r]);
        }
      }
    }

    // combine halves (exact: a+b == b+a), score, select
    #pragma unroll
    for (int r = 0; r < 4; ++r) {
      const float dA = accA[r] + __shfl_xor(accA[r], 32, 64);
      const float dB = accB[r] + __shfl_xor(accB[r], 32, 64);
      const float scA = fmaf(-2.f, dA, sA);
      const float scB = fmaf(-2.f, dB, sB);
      SEL1(scA, c0, r)
      SEL1(scB, c0 + 32, r)
    }

    __syncthreads();
  }

  // epilogue: lane r (0..3) owns row b0w+r
  if (lane < 4) {
    const int b = b0w + lane;
    const size_t base = (((size_t)b * A_ + a) * NCH + ch) * K_NN;
    #pragma unroll
    for (int j = 0; j < K_NN; ++j) {
      pscore[base + j] = best[j];
      pidx[base + j]   = bix[j];
    }
  }
}

// ---------------- K2: merge partial top-k, gather qvals, mean ----------------
__global__ __launch_bounds__(256) void merge_kernel(
    const float* __restrict__ pscore, const int* __restrict__ pidx,
    const float* __restrict__ qvals, float* __restrict__ qec)
{
  const int tt = blockIdx.x * 256 + threadIdx.x;  // tt = b*A + a
  if (tt >= B_ * A_) return;
  const int a = tt % A_;

  float best[K_NN]; int bix[K_NN];
  #pragma unroll
  for (int j = 0; j < K_NN; ++j) { best[j] = INFINITY; bix[j] = 0x7fffffff; }

  const float* ps = pscore + (size_t)tt * NCH * K_NN;
  const int*   pi = pidx   + (size_t)tt * NCH * K_NN;

  #pragma unroll
  for (int e = 0; e < NCH * K_NN; ++e) {
    float sc = ps[e]; int ci = pi[e];
    bool lt_last = (sc < best[K_NN-1]) || (sc == best[K_NN-1] && ci < bix[K_NN-1]);
    if (lt_last) {
      #pragma unroll
      for (int j = K_NN-1; j >= 1; --j) {
        bool  s1 = (best[j-1] > sc) || (best[j-1] == sc && bix[j-1] > ci);
        float nb = s1 ? best[j-1] : sc;
        int   ni = s1 ? bix[j-1]  : ci;
        bool  wr = (best[j] > sc) || (best[j] == sc && bix[j] > ci);
        if (wr) { best[j] = nb; bix[j] = ni; }
      }
      bool w0 = (best[0] > sc) || (best[0] == sc && bix[0] > ci);
      if (w0) { best[0] = sc; bix[0] = ci; }
    }
  }

  const float* qa = qvals + (size_t)a * C_;
  float s = 0.f;
  #pragma unroll
  for (int j = 0; j < K_NN; ++j) s += qa[bix[j]];
  qec[tt] = s / (float)K_NN;
}

// ---------------- K3: MLP + combine + argmax ----------------
__global__ __launch_bounds__(256) void mlp_kernel(
    const float* __restrict__ obs, const float* __restrict__ qec,
    const float* __restrict__ W1, const float* __restrict__ b1,
    const float* __restrict__ W2, const float* __restrict__ b2,
    const float* __restrict__ W3, const float* __restrict__ b3,
    float* __restrict__ out)
{
  const int wave = threadIdx.x >> 6;
  const int lane = threadIdx.x & 63;
  const int b = blockIdx.x * 4 + wave;

  float xv = obs[(size_t)b * 64 + lane];

  float acc = b1[lane];
  #pragma unroll 8
  for (int d = 0; d < 64; ++d)
    acc = fmaf(__shfl(xv, d, 64), W1[d * 64 + lane], acc);
  float h1 = fmaxf(acc, 0.f);

  float acc2 = b2[lane];
  #pragma unroll 8
  for (int d = 0; d < 64; ++d)
    acc2 = fmaf(__shfl(h1, d, 64), W2[d * 64 + lane], acc2);
  float h2 = fmaxf(acc2, 0.f);

  float p0 = h2 * W3[lane * 4 + 0];
  float p1 = h2 * W3[lane * 4 + 1];
  float p2 = h2 * W3[lane * 4 + 2];
  float p3 = h2 * W3[lane * 4 + 3];
  #pragma unroll
  for (int off = 32; off > 0; off >>= 1) {
    p0 += __shfl_xor(p0, off, 64);
    p1 += __shfl_xor(p1, off, 64);
    p2 += __shfl_xor(p2, off, 64);
    p3 += __shfl_xor(p3, off, 64);
  }

  if (lane == 0) {
    float q0 = 0.5f * (qec[b * 4 + 0] + (p0 + b3[0]));
    float q1 = 0.5f * (qec[b * 4 + 1] + (p1 + b3[1]));
    float q2 = 0.5f * (qec[b * 4 + 2] + (p2 + b3[2]));
    float q3 = 0.5f * (qec[b * 4 + 3] + (p3 + b3[3]));
    int am = 0; float m = q0;
    if (q1 > m) { m = q1; am = 1; }
    if (q2 > m) { m = q2; am = 2; }
    if (q3 > m) { m = q3; am = 3; }
    out[b] = (float)am;
    float* qrow = out + B_ + (size_t)b * 4;
    qrow[0] = q0; qrow[1] = q1; qrow[2] = q2; qrow[3] = q3;
  }
}

extern "C" void kernel_launch(void* const* d_in, const int* in_sizes, int n_in,
                              void* d_out, int out_size, void* d_ws, size_t ws_size,
                              hipStream_t stream) {
  const float* obs = (const float*)d_in[0];
  const float* ts  = (const float*)d_in[1];
  const float* qv  = (const float*)d_in[2];
  const float* W1  = (const float*)d_in[3];
  const float* b1  = (const float*)d_in[4];
  const float* W2  = (const float*)d_in[5];
  const float* b2  = (const float*)d_in[6];
  const float* W3  = (const float*)d_in[7];
  const float* b3  = (const float*)d_in[8];
  float* out = (float*)d_out;

  float* s2g    = (float*)d_ws;                                   // A*C
  float* qec    = s2g + (size_t)A_ * C_;                          // B*A
  float* pscore = qec + (size_t)B_ * A_;                          // B*A*NCH*K
  int*   pidx   = (int*)(pscore + (size_t)B_ * A_ * NCH * K_NN);  // same

  s2_kernel<<<dim3((A_ * C_ / 16 + 3) / 4), dim3(256), 0, stream>>>(ts, s2g);
  qec_kernel<<<dim3(256), dim3(512), 0, stream>>>(obs, ts, s2g, pscore, pidx);
  merge_kernel<<<dim3((B_ * A_ + 255) / 256), dim3(256), 0, stream>>>(pscore, pidx, qv, qec);
  mlp_kernel<<<dim3(B_ / 4), dim3(256), 0, stream>>>(obs, qec, W1, b1, W2, b2, W3, b3, out);
}